// Round 1
// baseline (2173.372 us; speedup 1.0000x reference)
//
#include <hip/hip_runtime.h>

#define NN 100000
#define NE 1600000
#define IND 128
#define NH 4
#define TOT 64

__device__ __forceinline__ unsigned fkey(float a) {
    unsigned u = __float_as_uint(a);
    return (u & 0x80000000u) ? ~u : (u | 0x80000000u);
}
__device__ __forceinline__ float funkey(unsigned u) {
    return __uint_as_float((u & 0x80000000u) ? (u & 0x7FFFFFFFu) : ~u);
}
__device__ __forceinline__ float lrelu(float a) { return a > 0.0f ? a : 0.2f * a; }

// K0: WT[c][k] = W[k][c], c<64 from lin_w, c>=64 from lin_res_w
__global__ void k0_wt(const float* __restrict__ lw, const float* __restrict__ lrw,
                      float* __restrict__ WT) {
    int idx = blockIdx.x * 256 + threadIdx.x;   // 16384
    int c = idx >> 7, k = idx & 127;
    float v = (c < 64) ? lw[k * 64 + c] : lrw[k * 64 + (c - 64)];
    WT[c * 128 + k] = v;
}

// K1: h = x@lin_w (cols 0..63), res = x@lin_res_w (cols 64..127) -> d_out
__global__ __launch_bounds__(256) void k1_gemm(const float* __restrict__ x,
                                               const float* __restrict__ WT,
                                               float* __restrict__ h,
                                               float* __restrict__ res) {
    __shared__ float sX[64][132];
    int t = threadIdx.x;
    int row0 = blockIdx.x * 64;
    #pragma unroll
    for (int i = 0; i < 8; ++i) {
        int lin = t + i * 256;              // 0..2047
        int r = lin >> 5;                   // 0..63
        int kv = (lin & 31) << 2;           // 0..124
        float4 v = make_float4(0.f, 0.f, 0.f, 0.f);
        int gr = row0 + r;
        if (gr < NN) v = *(const float4*)(x + (size_t)gr * IND + kv);
        *(float4*)(&sX[r][kv]) = v;
    }
    __syncthreads();
    int cg = t & 15, rg = t >> 4;
    int c0 = cg * 8, r0 = rg * 4;
    float acc[4][8];
    #pragma unroll
    for (int rr = 0; rr < 4; ++rr)
        #pragma unroll
        for (int j = 0; j < 8; ++j) acc[rr][j] = 0.f;

    for (int k = 0; k < 128; k += 4) {
        float4 xk[4];
        #pragma unroll
        for (int rr = 0; rr < 4; ++rr) xk[rr] = *(const float4*)(&sX[r0 + rr][k]);
        float4 wv[8];
        #pragma unroll
        for (int j = 0; j < 8; ++j) wv[j] = *(const float4*)(WT + (c0 + j) * 128 + k);
        #pragma unroll
        for (int rr = 0; rr < 4; ++rr) {
            #pragma unroll
            for (int j = 0; j < 8; ++j) {
                acc[rr][j] = fmaf(xk[rr].x, wv[j].x, acc[rr][j]);
                acc[rr][j] = fmaf(xk[rr].y, wv[j].y, acc[rr][j]);
                acc[rr][j] = fmaf(xk[rr].z, wv[j].z, acc[rr][j]);
                acc[rr][j] = fmaf(xk[rr].w, wv[j].w, acc[rr][j]);
            }
        }
    }
    #pragma unroll
    for (int rr = 0; rr < 4; ++rr) {
        int gr = row0 + r0 + rr;
        if (gr >= NN) continue;
        float4 v0 = make_float4(acc[rr][0], acc[rr][1], acc[rr][2], acc[rr][3]);
        float4 v1 = make_float4(acc[rr][4], acc[rr][5], acc[rr][6], acc[rr][7]);
        if (c0 < 64) {
            *(float4*)(h + (size_t)gr * TOT + c0) = v0;
            *(float4*)(h + (size_t)gr * TOT + c0 + 4) = v1;
        } else {
            *(float4*)(res + (size_t)gr * TOT + (c0 - 64)) = v0;
            *(float4*)(res + (size_t)gr * TOT + (c0 - 64) + 4) = v1;
        }
    }
}

// K1b: al[n,h] = h[n,h,:]·att_l[h], ar likewise
__global__ void k1b_alpha(const float* __restrict__ h, const float* __restrict__ attl,
                          const float* __restrict__ attr, float* __restrict__ al,
                          float* __restrict__ ar) {
    int idx = blockIdx.x * 256 + threadIdx.x;
    if (idx >= NN * NH) return;
    int n = idx >> 2, hh = idx & 3;
    const float4* hp = (const float4*)(h + (size_t)n * TOT + hh * 16);
    const float4* lp = (const float4*)(attl + hh * 16);
    const float4* rp = (const float4*)(attr + hh * 16);
    float sl = 0.f, sr = 0.f;
    #pragma unroll
    for (int i = 0; i < 4; ++i) {
        float4 hv = hp[i], lv = lp[i], rv = rp[i];
        sl += hv.x * lv.x + hv.y * lv.y + hv.z * lv.z + hv.w * lv.w;
        sr += hv.x * rv.x + hv.y * rv.y + hv.z * rv.z + hv.w * rv.w;
    }
    al[idx] = sl;
    ar[idx] = sr;
}

// K2: per-edge alpha + atomicMax per (dst,head)
__global__ void k2_edge(const int* __restrict__ src, const int* __restrict__ dst,
                        const float* __restrict__ ew, const float* __restrict__ al,
                        const float* __restrict__ ar, float* __restrict__ alpha,
                        unsigned* __restrict__ nmax) {
    int e = blockIdx.x * 256 + threadIdx.x;
    if (e >= NE) return;
    int s = src[e], d = dst[e];
    float w = ew[e];
    float4 a = *(const float4*)(al + (size_t)s * 4);
    float4 b = *(const float4*)(ar + (size_t)d * 4);
    float4 o;
    o.x = lrelu(w * (a.x + b.x));
    o.y = lrelu(w * (a.y + b.y));
    o.z = lrelu(w * (a.z + b.z));
    o.w = lrelu(w * (a.w + b.w));
    *(float4*)(alpha + (size_t)e * 4) = o;
    unsigned* mp = nmax + (size_t)d * 4;
    atomicMax(mp + 0, fkey(o.x));
    atomicMax(mp + 1, fkey(o.y));
    atomicMax(mp + 2, fkey(o.z));
    atomicMax(mp + 3, fkey(o.w));
}

// K3: e = exp(alpha - max[dst]); atomicAdd sums
__global__ void k3_exp(const int* __restrict__ dst, float* __restrict__ alpha,
                       const unsigned* __restrict__ nmax, float* __restrict__ nsum) {
    int e = blockIdx.x * 256 + threadIdx.x;
    if (e >= NE) return;
    int d = dst[e];
    float4 a = *(const float4*)(alpha + (size_t)e * 4);
    uint4 mk = *(const uint4*)(nmax + (size_t)d * 4);
    float4 o;
    o.x = __expf(a.x - funkey(mk.x));
    o.y = __expf(a.y - funkey(mk.y));
    o.z = __expf(a.z - funkey(mk.z));
    o.w = __expf(a.w - funkey(mk.w));
    *(float4*)(alpha + (size_t)e * 4) = o;
    float* sp = nsum + (size_t)d * 4;
    atomicAdd(sp + 0, o.x);
    atomicAdd(sp + 1, o.y);
    atomicAdd(sp + 2, o.z);
    atomicAdd(sp + 3, o.w);
}

// K4: scatter msg = h[src]*coeff into agg (16 threads per edge, 4 floats each)
__global__ void k4_scatter(const int* __restrict__ src, const int* __restrict__ dst,
                           const float* __restrict__ alpha, const float* __restrict__ nsum,
                           const float* __restrict__ h, float* __restrict__ agg) {
    int t = threadIdx.x;
    int e = blockIdx.x * 16 + (t >> 4);
    if (e >= NE) return;
    int part = t & 15;
    int s = src[e], d = dst[e];
    int head = part >> 2;
    float coef = alpha[(size_t)e * 4 + head] / nsum[(size_t)d * 4 + head];
    float4 hv = *(const float4*)(h + (size_t)s * TOT + part * 4);
    float* ap = agg + (size_t)d * TOT + part * 4;
    atomicAdd(ap + 0, hv.x * coef);
    atomicAdd(ap + 1, hv.y * coef);
    atomicAdd(ap + 2, hv.z * coef);
    atomicAdd(ap + 3, hv.w * coef);
}

// K5: out = elu(agg) + residual (residual already in out)
__global__ void k5_out(const float* __restrict__ agg, float* __restrict__ out) {
    int i = blockIdx.x * 256 + threadIdx.x;
    if (i >= NN * 16) return;
    float4 a = *(const float4*)(agg + (size_t)i * 4);
    float4 r = *(const float4*)(out + (size_t)i * 4);
    float4 o;
    o.x = (a.x > 0.f ? a.x : expm1f(a.x)) + r.x;
    o.y = (a.y > 0.f ? a.y : expm1f(a.y)) + r.y;
    o.z = (a.z > 0.f ? a.z : expm1f(a.z)) + r.z;
    o.w = (a.w > 0.f ? a.w : expm1f(a.w)) + r.w;
    *(float4*)(out + (size_t)i * 4) = o;
}

extern "C" void kernel_launch(void* const* d_in, const int* in_sizes, int n_in,
                              void* d_out, int out_size, void* d_ws, size_t ws_size,
                              hipStream_t stream) {
    const float* x    = (const float*)d_in[0];
    const int*   ei   = (const int*)d_in[1];
    const float* ew   = (const float*)d_in[2];
    const float* lw   = (const float*)d_in[3];
    const float* attl = (const float*)d_in[4];
    const float* attr = (const float*)d_in[5];
    const float* lrw  = (const float*)d_in[6];
    float* out = (float*)d_out;
    const int* src = ei;
    const int* dst = ei + NE;

    char* w = (char*)d_ws;
    float* WT = (float*)w;       w += 128 * 128 * 4;
    float* h = (float*)w;        w += (size_t)NN * TOT * 4;
    float* al = (float*)w;       w += (size_t)NN * 4 * 4;
    float* ar = (float*)w;       w += (size_t)NN * 4 * 4;
    float* alpha = (float*)w;    w += (size_t)NE * 4 * 4;
    unsigned* nmax = (unsigned*)w; w += (size_t)NN * 4 * 4;
    float* nsum = (float*)w;     w += (size_t)NN * 4 * 4;
    float* agg = (float*)w;      w += (size_t)NN * TOT * 4;
    size_t needed = (size_t)(w - (char*)d_ws);
    if (ws_size < needed) return;  // fail loudly (validation will catch)

    hipMemsetAsync(nmax, 0, (size_t)NN * 4 * 4, stream);
    hipMemsetAsync(nsum, 0, (size_t)NN * 4 * 4, stream);
    hipMemsetAsync(agg, 0, (size_t)NN * TOT * 4, stream);

    k0_wt<<<64, 256, 0, stream>>>(lw, lrw, WT);
    k1_gemm<<<(NN + 63) / 64, 256, 0, stream>>>(x, WT, h, out);
    k1b_alpha<<<(NN * NH + 255) / 256, 256, 0, stream>>>(h, attl, attr, al, ar);
    k2_edge<<<(NE + 255) / 256, 256, 0, stream>>>(src, dst, ew, al, ar, alpha, nmax);
    k3_exp<<<(NE + 255) / 256, 256, 0, stream>>>(dst, alpha, nmax, nsum);
    k4_scatter<<<NE / 16, 256, 0, stream>>>(src, dst, alpha, nsum, h, agg);
    k5_out<<<(NN * 16 + 255) / 256, 256, 0, stream>>>(agg, out);
}

// Round 2
// 459.053 us; speedup vs baseline: 4.7345x; 4.7345x over previous
//
#include <hip/hip_runtime.h>
#include <float.h>

#define NN 100000
#define NE 1600000
#define IND 128
#define NH 4
#define TOT 64
#define NB ((NN + 255) / 256)   // 391 blocks for scan

__device__ __forceinline__ float lrelu(float a) { return a > 0.0f ? a : 0.2f * a; }

// K0: WT[c][k] = W[k][c], c<64 from lin_w, c>=64 from lin_res_w
__global__ void k0_wt(const float* __restrict__ lw, const float* __restrict__ lrw,
                      float* __restrict__ WT) {
    int idx = blockIdx.x * 256 + threadIdx.x;   // 16384
    int c = idx >> 7, k = idx & 127;
    float v = (c < 64) ? lw[k * 64 + c] : lrw[k * 64 + (c - 64)];
    WT[c * 128 + k] = v;
}

// K1: h = x@lin_w (cols 0..63), res = x@lin_res_w (cols 64..127) -> d_out
__global__ __launch_bounds__(256) void k1_gemm(const float* __restrict__ x,
                                               const float* __restrict__ WT,
                                               float* __restrict__ h,
                                               float* __restrict__ res) {
    __shared__ float sX[64][132];
    int t = threadIdx.x;
    int row0 = blockIdx.x * 64;
    #pragma unroll
    for (int i = 0; i < 8; ++i) {
        int lin = t + i * 256;              // 0..2047
        int r = lin >> 5;                   // 0..63
        int kv = (lin & 31) << 2;           // 0..124
        float4 v = make_float4(0.f, 0.f, 0.f, 0.f);
        int gr = row0 + r;
        if (gr < NN) v = *(const float4*)(x + (size_t)gr * IND + kv);
        *(float4*)(&sX[r][kv]) = v;
    }
    __syncthreads();
    int cg = t & 15, rg = t >> 4;
    int c0 = cg * 8, r0 = rg * 4;
    float acc[4][8];
    #pragma unroll
    for (int rr = 0; rr < 4; ++rr)
        #pragma unroll
        for (int j = 0; j < 8; ++j) acc[rr][j] = 0.f;

    for (int k = 0; k < 128; k += 4) {
        float4 xk[4];
        #pragma unroll
        for (int rr = 0; rr < 4; ++rr) xk[rr] = *(const float4*)(&sX[r0 + rr][k]);
        float4 wv[8];
        #pragma unroll
        for (int j = 0; j < 8; ++j) wv[j] = *(const float4*)(WT + (c0 + j) * 128 + k);
        #pragma unroll
        for (int rr = 0; rr < 4; ++rr) {
            #pragma unroll
            for (int j = 0; j < 8; ++j) {
                acc[rr][j] = fmaf(xk[rr].x, wv[j].x, acc[rr][j]);
                acc[rr][j] = fmaf(xk[rr].y, wv[j].y, acc[rr][j]);
                acc[rr][j] = fmaf(xk[rr].z, wv[j].z, acc[rr][j]);
                acc[rr][j] = fmaf(xk[rr].w, wv[j].w, acc[rr][j]);
            }
        }
    }
    #pragma unroll
    for (int rr = 0; rr < 4; ++rr) {
        int gr = row0 + r0 + rr;
        if (gr >= NN) continue;
        float4 v0 = make_float4(acc[rr][0], acc[rr][1], acc[rr][2], acc[rr][3]);
        float4 v1 = make_float4(acc[rr][4], acc[rr][5], acc[rr][6], acc[rr][7]);
        if (c0 < 64) {
            *(float4*)(h + (size_t)gr * TOT + c0) = v0;
            *(float4*)(h + (size_t)gr * TOT + c0 + 4) = v1;
        } else {
            *(float4*)(res + (size_t)gr * TOT + (c0 - 64)) = v0;
            *(float4*)(res + (size_t)gr * TOT + (c0 - 64) + 4) = v1;
        }
    }
}

// K1b: al[n,h] = h[n,h,:]·att_l[h], ar likewise
__global__ void k1b_alpha(const float* __restrict__ h, const float* __restrict__ attl,
                          const float* __restrict__ attr, float* __restrict__ al,
                          float* __restrict__ ar) {
    int idx = blockIdx.x * 256 + threadIdx.x;
    if (idx >= NN * NH) return;
    int n = idx >> 2, hh = idx & 3;
    const float4* hp = (const float4*)(h + (size_t)n * TOT + hh * 16);
    const float4* lp = (const float4*)(attl + hh * 16);
    const float4* rp = (const float4*)(attr + hh * 16);
    float sl = 0.f, sr = 0.f;
    #pragma unroll
    for (int i = 0; i < 4; ++i) {
        float4 hv = hp[i], lv = lp[i], rv = rp[i];
        sl += hv.x * lv.x + hv.y * lv.y + hv.z * lv.z + hv.w * lv.w;
        sr += hv.x * rv.x + hv.y * rv.y + hv.z * rv.z + hv.w * rv.w;
    }
    al[idx] = sl;
    ar[idx] = sr;
}

// Histogram of destination degrees
__global__ void khist(const int* __restrict__ dst, int* __restrict__ deg) {
    int e = blockIdx.x * 256 + threadIdx.x;
    if (e >= NE) return;
    atomicAdd(deg + dst[e], 1);
}

// Scan stage 1: per-block sums of deg
__global__ void kscan_block(const int* __restrict__ deg, int* __restrict__ bsum) {
    __shared__ int s[256];
    int i = blockIdx.x * 256 + threadIdx.x;
    s[threadIdx.x] = (i < NN) ? deg[i] : 0;
    __syncthreads();
    for (int off = 128; off > 0; off >>= 1) {
        if (threadIdx.x < off) s[threadIdx.x] += s[threadIdx.x + off];
        __syncthreads();
    }
    if (threadIdx.x == 0) bsum[blockIdx.x] = s[0];
}

// Scan stage 2: exclusive scan of block sums (single block, NB<=512)
__global__ void kscan_top(int* __restrict__ bsum) {
    __shared__ int s[512];
    int v = (threadIdx.x < NB) ? bsum[threadIdx.x] : 0;
    s[threadIdx.x] = v;
    __syncthreads();
    for (int off = 1; off < 512; off <<= 1) {
        int tv = (threadIdx.x >= off) ? s[threadIdx.x - off] : 0;
        __syncthreads();
        s[threadIdx.x] += tv;
        __syncthreads();
    }
    if (threadIdx.x < NB) bsum[threadIdx.x] = s[threadIdx.x] - v;  // exclusive
}

// Scan stage 3: per-element exclusive scan + block offset -> rowptr & cursor
__global__ void kscan_final(const int* __restrict__ deg, const int* __restrict__ bsum,
                            int* __restrict__ rowptr, int* __restrict__ cursor) {
    __shared__ int s[256];
    int i = blockIdx.x * 256 + threadIdx.x;
    int v = (i < NN) ? deg[i] : 0;
    s[threadIdx.x] = v;
    __syncthreads();
    for (int off = 1; off < 256; off <<= 1) {
        int tv = (threadIdx.x >= off) ? s[threadIdx.x - off] : 0;
        __syncthreads();
        s[threadIdx.x] += tv;
        __syncthreads();
    }
    if (i < NN) {
        int ex = bsum[blockIdx.x] + s[threadIdx.x] - v;
        rowptr[i] = ex;
        cursor[i] = ex;
        if (i == NN - 1) rowptr[NN] = ex + v;
    }
}

// Fill CSR: per-edge alpha (leaky_relu'd) + permuted src, bucketed by dst
__global__ void kfill(const int* __restrict__ src, const int* __restrict__ dst,
                      const float* __restrict__ ew, const float* __restrict__ al,
                      const float* __restrict__ ar, int* __restrict__ cursor,
                      int* __restrict__ psrc, float* __restrict__ palpha) {
    int e = blockIdx.x * 256 + threadIdx.x;
    if (e >= NE) return;
    int s = src[e], d = dst[e];
    float w = ew[e];
    float4 a = *(const float4*)(al + (size_t)s * 4);
    float4 b = *(const float4*)(ar + (size_t)d * 4);
    float4 o;
    o.x = lrelu(w * (a.x + b.x));
    o.y = lrelu(w * (a.y + b.y));
    o.z = lrelu(w * (a.z + b.z));
    o.w = lrelu(w * (a.w + b.w));
    int pos = atomicAdd(cursor + d, 1);
    psrc[pos] = s;
    *(float4*)(palpha + (size_t)pos * 4) = o;
}

// Aggregate: 16 lanes per node. softmax (max, sum via shfl) + gather h[src]*coeff
// + ELU + residual (residual already in out), single store. No atomics.
__global__ __launch_bounds__(256) void kagg(const int* __restrict__ rowptr,
                                            const int* __restrict__ psrc,
                                            const float* __restrict__ palpha,
                                            const float* __restrict__ h,
                                            float* __restrict__ out) {
    int t = threadIdx.x;
    int node = blockIdx.x * 16 + (t >> 4);
    if (node >= NN) return;
    int part = t & 15;
    int head = part >> 2;
    int beg = rowptr[node], end = rowptr[node + 1];

    // pass 1a: per-head max over incoming edges (strided across 16 lanes)
    float4 m = make_float4(-FLT_MAX, -FLT_MAX, -FLT_MAX, -FLT_MAX);
    for (int p = beg + part; p < end; p += 16) {
        float4 a = *(const float4*)(palpha + (size_t)p * 4);
        m.x = fmaxf(m.x, a.x); m.y = fmaxf(m.y, a.y);
        m.z = fmaxf(m.z, a.z); m.w = fmaxf(m.w, a.w);
    }
    #pragma unroll
    for (int off = 1; off < 16; off <<= 1) {
        m.x = fmaxf(m.x, __shfl_xor(m.x, off));
        m.y = fmaxf(m.y, __shfl_xor(m.y, off));
        m.z = fmaxf(m.z, __shfl_xor(m.z, off));
        m.w = fmaxf(m.w, __shfl_xor(m.w, off));
    }
    // pass 1b: per-head sum of exp
    float4 sm = make_float4(0.f, 0.f, 0.f, 0.f);
    for (int p = beg + part; p < end; p += 16) {
        float4 a = *(const float4*)(palpha + (size_t)p * 4);
        sm.x += __expf(a.x - m.x); sm.y += __expf(a.y - m.y);
        sm.z += __expf(a.z - m.z); sm.w += __expf(a.w - m.w);
    }
    #pragma unroll
    for (int off = 1; off < 16; off <<= 1) {
        sm.x += __shfl_xor(sm.x, off);
        sm.y += __shfl_xor(sm.y, off);
        sm.z += __shfl_xor(sm.z, off);
        sm.w += __shfl_xor(sm.w, off);
    }
    float msel = (head == 0) ? m.x : (head == 1) ? m.y : (head == 2) ? m.z : m.w;
    float ssel = (head == 0) ? sm.x : (head == 1) ? sm.y : (head == 2) ? sm.z : sm.w;
    float rinv = (ssel > 0.f) ? 1.f / ssel : 0.f;

    // pass 2: gather-accumulate h[src] * coeff
    float4 acc = make_float4(0.f, 0.f, 0.f, 0.f);
    for (int p = beg; p < end; ++p) {
        int s = psrc[p];                                  // broadcast across 16 lanes
        float a = palpha[(size_t)p * 4 + head];           // broadcast across 4 lanes
        float c = __expf(a - msel) * rinv;
        float4 hv = *(const float4*)(h + (size_t)s * TOT + part * 4);  // 256B/edge segment
        acc.x = fmaf(hv.x, c, acc.x);
        acc.y = fmaf(hv.y, c, acc.y);
        acc.z = fmaf(hv.z, c, acc.z);
        acc.w = fmaf(hv.w, c, acc.w);
    }
    float* op = out + (size_t)node * TOT + part * 4;
    float4 r = *(const float4*)op;
    float4 o;
    o.x = (acc.x > 0.f ? acc.x : expm1f(acc.x)) + r.x;
    o.y = (acc.y > 0.f ? acc.y : expm1f(acc.y)) + r.y;
    o.z = (acc.z > 0.f ? acc.z : expm1f(acc.z)) + r.z;
    o.w = (acc.w > 0.f ? acc.w : expm1f(acc.w)) + r.w;
    *(float4*)op = o;
}

extern "C" void kernel_launch(void* const* d_in, const int* in_sizes, int n_in,
                              void* d_out, int out_size, void* d_ws, size_t ws_size,
                              hipStream_t stream) {
    const float* x    = (const float*)d_in[0];
    const int*   ei   = (const int*)d_in[1];
    const float* ew   = (const float*)d_in[2];
    const float* lw   = (const float*)d_in[3];
    const float* attl = (const float*)d_in[4];
    const float* attr = (const float*)d_in[5];
    const float* lrw  = (const float*)d_in[6];
    float* out = (float*)d_out;
    const int* src = ei;
    const int* dst = ei + NE;

    char* w = (char*)d_ws;
    auto alloc = [&](size_t bytes) { char* p = w; w += (bytes + 255) & ~(size_t)255; return p; };
    float* WT     = (float*)alloc(128 * 128 * 4);
    float* h      = (float*)alloc((size_t)NN * TOT * 4);
    float* al     = (float*)alloc((size_t)NN * 4 * 4);
    float* ar     = (float*)alloc((size_t)NN * 4 * 4);
    int*   deg    = (int*)alloc((size_t)NN * 4);
    int*   rowptr = (int*)alloc((size_t)(NN + 1) * 4);
    int*   cursor = (int*)alloc((size_t)NN * 4);
    int*   bsum   = (int*)alloc((size_t)512 * 4);
    int*   psrc   = (int*)alloc((size_t)NE * 4);
    float* palpha = (float*)alloc((size_t)NE * 4 * 4);
    size_t needed = (size_t)(w - (char*)d_ws);
    if (ws_size < needed) return;  // fail loudly (validation will catch)

    hipMemsetAsync(deg, 0, (size_t)NN * 4, stream);

    k0_wt<<<64, 256, 0, stream>>>(lw, lrw, WT);
    k1_gemm<<<(NN + 63) / 64, 256, 0, stream>>>(x, WT, h, out);
    k1b_alpha<<<(NN * NH + 255) / 256, 256, 0, stream>>>(h, attl, attr, al, ar);
    khist<<<(NE + 255) / 256, 256, 0, stream>>>(dst, deg);
    kscan_block<<<NB, 256, 0, stream>>>(deg, bsum);
    kscan_top<<<1, 512, 0, stream>>>(bsum);
    kscan_final<<<NB, 256, 0, stream>>>(deg, bsum, rowptr, cursor);
    kfill<<<(NE + 255) / 256, 256, 0, stream>>>(src, dst, ew, al, ar, cursor, psrc, palpha);
    kagg<<<(NN + 15) / 16, 256, 0, stream>>>(rowptr, psrc, palpha, h, out);
}

// Round 3
// 284.681 us; speedup vs baseline: 7.6344x; 1.6125x over previous
//
#include <hip/hip_runtime.h>
#include <float.h>

#define NN 100000
#define NE 1600000
#define IND 128
#define NH 4
#define TOT 64
#define NCOL 144                 // 64 h | 64 res | 4 al | 4 ar | 8 pad
#define NB ((NN + 255) / 256)    // scan blocks

typedef __attribute__((ext_vector_type(8))) short short8;
typedef __attribute__((ext_vector_type(4))) float f32x4;

__device__ __forceinline__ float lrelu(float a) { return a > 0.0f ? a : 0.2f * a; }

__device__ __forceinline__ unsigned short bf16_rne(float f) {
    unsigned u = __float_as_uint(f);
    unsigned r = u + 0x7FFFu + ((u >> 16) & 1u);
    return (unsigned short)(r >> 16);
}
__device__ __forceinline__ float bf16_to_f(unsigned short h) {
    return __uint_as_float(((unsigned)h) << 16);
}

// K0: build split-bf16 transposed weights WT[c][k], c in [0,144)
// c<64: lin_w col; c<128: lin_res_w col; c<132: lin_w@att_l[head]; c<136: lin_w@att_r; else 0
__global__ void k0_wt(const float* __restrict__ lw, const float* __restrict__ lrw,
                      const float* __restrict__ attl, const float* __restrict__ attr,
                      unsigned short* __restrict__ WTh, unsigned short* __restrict__ WTl) {
    int idx = blockIdx.x * 256 + threadIdx.x;   // NCOL*128 = 18432
    if (idx >= NCOL * 128) return;
    int c = idx >> 7, k = idx & 127;
    float v = 0.f;
    if (c < 64) v = lw[k * 64 + c];
    else if (c < 128) v = lrw[k * 64 + (c - 64)];
    else if (c < 132) {
        int hh = c - 128; float s = 0.f;
        #pragma unroll
        for (int j = 0; j < 16; ++j) s += lw[k * 64 + hh * 16 + j] * attl[hh * 16 + j];
        v = s;
    } else if (c < 136) {
        int hh = c - 132; float s = 0.f;
        #pragma unroll
        for (int j = 0; j < 16; ++j) s += lw[k * 64 + hh * 16 + j] * attr[hh * 16 + j];
        v = s;
    }
    unsigned short hi = bf16_rne(v);
    float hif = bf16_to_f(hi);
    WTh[idx] = hi;
    WTl[idx] = bf16_rne(v - hif);
}

// K1: MFMA GEMM, x[100000x128] @ WT^T[128x144] via split-bf16 (3 mfma per tile)
// outputs: hbf (bf16 h), res->d_out (f32), al, ar
__global__ __launch_bounds__(256) void k1_mfma(const float* __restrict__ x,
        const unsigned short* __restrict__ WTh, const unsigned short* __restrict__ WTl,
        unsigned short* __restrict__ hbf, float* __restrict__ res,
        float* __restrict__ al, float* __restrict__ ar) {
    int lane = threadIdx.x & 63;
    int wave = threadIdx.x >> 6;
    int row0 = blockIdx.x * 128 + wave * 32;
    int lr = lane & 15;     // A-row / B-col / C-col within tile
    int lk = lane >> 4;     // k-group (0..3)

    f32x4 acc[2][9];
    #pragma unroll
    for (int mt = 0; mt < 2; ++mt)
        #pragma unroll
        for (int nt = 0; nt < 9; ++nt) acc[mt][nt] = (f32x4)(0.f);

    #pragma unroll
    for (int ks = 0; ks < 4; ++ks) {
        int k0 = ks * 32 + lk * 8;
        short8 bh[9], bl[9];
        #pragma unroll
        for (int nt = 0; nt < 9; ++nt) {
            bh[nt] = *(const short8*)(WTh + (size_t)(nt * 16 + lr) * 128 + k0);
            bl[nt] = *(const short8*)(WTl + (size_t)(nt * 16 + lr) * 128 + k0);
        }
        #pragma unroll
        for (int mt = 0; mt < 2; ++mt) {
            int row = row0 + mt * 16 + lr;
            float4 v0 = make_float4(0.f, 0.f, 0.f, 0.f), v1 = v0;
            if (row < NN) {
                v0 = *(const float4*)(x + (size_t)row * IND + k0);
                v1 = *(const float4*)(x + (size_t)row * IND + k0 + 4);
            }
            float vs[8] = {v0.x, v0.y, v0.z, v0.w, v1.x, v1.y, v1.z, v1.w};
            short8 ah, alo;
            #pragma unroll
            for (int i = 0; i < 8; ++i) {
                unsigned short hi = bf16_rne(vs[i]);
                ah[i] = (short)hi;
                alo[i] = (short)bf16_rne(vs[i] - bf16_to_f(hi));
            }
            #pragma unroll
            for (int nt = 0; nt < 9; ++nt) {
                acc[mt][nt] = __builtin_amdgcn_mfma_f32_16x16x32_bf16(ah, bh[nt], acc[mt][nt], 0, 0, 0);
                acc[mt][nt] = __builtin_amdgcn_mfma_f32_16x16x32_bf16(alo, bh[nt], acc[mt][nt], 0, 0, 0);
                acc[mt][nt] = __builtin_amdgcn_mfma_f32_16x16x32_bf16(ah, bl[nt], acc[mt][nt], 0, 0, 0);
            }
        }
    }
    // epilogue: C elem r of lane = C[(lane>>4)*4 + r][lane&15]
    #pragma unroll
    for (int mt = 0; mt < 2; ++mt) {
        #pragma unroll
        for (int nt = 0; nt < 9; ++nt) {
            int c = nt * 16 + lr;
            #pragma unroll
            for (int r = 0; r < 4; ++r) {
                int row = row0 + mt * 16 + lk * 4 + r;
                if (row >= NN) continue;
                float v = acc[mt][nt][r];
                if (c < 64)       hbf[(size_t)row * TOT + c] = bf16_rne(v);
                else if (c < 128) res[(size_t)row * TOT + (c - 64)] = v;
                else if (c < 132) al[(size_t)row * 4 + (c - 128)] = v;
                else if (c < 136) ar[(size_t)row * 4 + (c - 132)] = v;
            }
        }
    }
}

// Histogram of destination degrees
__global__ void khist(const int* __restrict__ dst, int* __restrict__ deg) {
    int e = blockIdx.x * 256 + threadIdx.x;
    if (e >= NE) return;
    atomicAdd(deg + dst[e], 1);
}

__global__ void kscan_block(const int* __restrict__ deg, int* __restrict__ bsum) {
    __shared__ int s[256];
    int i = blockIdx.x * 256 + threadIdx.x;
    s[threadIdx.x] = (i < NN) ? deg[i] : 0;
    __syncthreads();
    for (int off = 128; off > 0; off >>= 1) {
        if (threadIdx.x < off) s[threadIdx.x] += s[threadIdx.x + off];
        __syncthreads();
    }
    if (threadIdx.x == 0) bsum[blockIdx.x] = s[0];
}

__global__ void kscan_top(int* __restrict__ bsum) {
    __shared__ int s[512];
    int v = (threadIdx.x < NB) ? bsum[threadIdx.x] : 0;
    s[threadIdx.x] = v;
    __syncthreads();
    for (int off = 1; off < 512; off <<= 1) {
        int tv = (threadIdx.x >= off) ? s[threadIdx.x - off] : 0;
        __syncthreads();
        s[threadIdx.x] += tv;
        __syncthreads();
    }
    if (threadIdx.x < NB) bsum[threadIdx.x] = s[threadIdx.x] - v;  // exclusive
}

__global__ void kscan_final(const int* __restrict__ deg, const int* __restrict__ bsum,
                            int* __restrict__ rowptr, int* __restrict__ cursor) {
    __shared__ int s[256];
    int i = blockIdx.x * 256 + threadIdx.x;
    int v = (i < NN) ? deg[i] : 0;
    s[threadIdx.x] = v;
    __syncthreads();
    for (int off = 1; off < 256; off <<= 1) {
        int tv = (threadIdx.x >= off) ? s[threadIdx.x - off] : 0;
        __syncthreads();
        s[threadIdx.x] += tv;
        __syncthreads();
    }
    if (i < NN) {
        int ex = bsum[blockIdx.x] + s[threadIdx.x] - v;
        rowptr[i] = ex;
        cursor[i] = ex;
        if (i == NN - 1) rowptr[NN] = ex + v;
    }
}

// Fill CSR: per-edge alpha (leaky_relu'd) + permuted src, bucketed by dst
__global__ void kfill(const int* __restrict__ src, const int* __restrict__ dst,
                      const float* __restrict__ ew, const float* __restrict__ al,
                      const float* __restrict__ ar, int* __restrict__ cursor,
                      int* __restrict__ psrc, float* __restrict__ palpha) {
    int e = blockIdx.x * 256 + threadIdx.x;
    if (e >= NE) return;
    int s = src[e], d = dst[e];
    float w = ew[e];
    float4 a = *(const float4*)(al + (size_t)s * 4);
    float4 b = *(const float4*)(ar + (size_t)d * 4);
    float4 o;
    o.x = lrelu(w * (a.x + b.x));
    o.y = lrelu(w * (a.y + b.y));
    o.z = lrelu(w * (a.z + b.z));
    o.w = lrelu(w * (a.w + b.w));
    int pos = atomicAdd(cursor + d, 1);
    psrc[pos] = s;
    *(float4*)(palpha + (size_t)pos * 4) = o;
}

// Aggregate per node: softmax over incoming edges + gather bf16 h[src]*coeff
// + ELU + residual (already in out), no atomics.
__global__ __launch_bounds__(256) void kagg(const int* __restrict__ rowptr,
                                            const int* __restrict__ psrc,
                                            const float* __restrict__ palpha,
                                            const unsigned short* __restrict__ hbf,
                                            float* __restrict__ out) {
    int t = threadIdx.x;
    int node = blockIdx.x * 16 + (t >> 4);
    if (node >= NN) return;
    int part = t & 15;
    int head = part >> 2;
    int beg = rowptr[node], end = rowptr[node + 1];

    float4 m = make_float4(-FLT_MAX, -FLT_MAX, -FLT_MAX, -FLT_MAX);
    for (int p = beg + part; p < end; p += 16) {
        float4 a = *(const float4*)(palpha + (size_t)p * 4);
        m.x = fmaxf(m.x, a.x); m.y = fmaxf(m.y, a.y);
        m.z = fmaxf(m.z, a.z); m.w = fmaxf(m.w, a.w);
    }
    #pragma unroll
    for (int off = 1; off < 16; off <<= 1) {
        m.x = fmaxf(m.x, __shfl_xor(m.x, off));
        m.y = fmaxf(m.y, __shfl_xor(m.y, off));
        m.z = fmaxf(m.z, __shfl_xor(m.z, off));
        m.w = fmaxf(m.w, __shfl_xor(m.w, off));
    }
    float4 sm = make_float4(0.f, 0.f, 0.f, 0.f);
    for (int p = beg + part; p < end; p += 16) {
        float4 a = *(const float4*)(palpha + (size_t)p * 4);
        sm.x += __expf(a.x - m.x); sm.y += __expf(a.y - m.y);
        sm.z += __expf(a.z - m.z); sm.w += __expf(a.w - m.w);
    }
    #pragma unroll
    for (int off = 1; off < 16; off <<= 1) {
        sm.x += __shfl_xor(sm.x, off);
        sm.y += __shfl_xor(sm.y, off);
        sm.z += __shfl_xor(sm.z, off);
        sm.w += __shfl_xor(sm.w, off);
    }
    float msel = (head == 0) ? m.x : (head == 1) ? m.y : (head == 2) ? m.z : m.w;
    float ssel = (head == 0) ? sm.x : (head == 1) ? sm.y : (head == 2) ? sm.z : sm.w;
    float rinv = (ssel > 0.f) ? 1.f / ssel : 0.f;

    float4 acc = make_float4(0.f, 0.f, 0.f, 0.f);
    for (int p = beg; p < end; ++p) {
        int s = psrc[p];                            // broadcast across 16 lanes
        float a = palpha[(size_t)p * 4 + head];
        float c = __expf(a - msel) * rinv;
        uint2 u = *(const uint2*)(hbf + (size_t)s * TOT + part * 4);  // 4 bf16 = 8B
        float h0 = __uint_as_float(u.x << 16);
        float h1 = __uint_as_float(u.x & 0xFFFF0000u);
        float h2 = __uint_as_float(u.y << 16);
        float h3 = __uint_as_float(u.y & 0xFFFF0000u);
        acc.x = fmaf(h0, c, acc.x);
        acc.y = fmaf(h1, c, acc.y);
        acc.z = fmaf(h2, c, acc.z);
        acc.w = fmaf(h3, c, acc.w);
    }
    float* op = out + (size_t)node * TOT + part * 4;
    float4 r = *(const float4*)op;
    float4 o;
    o.x = (acc.x > 0.f ? acc.x : expm1f(acc.x)) + r.x;
    o.y = (acc.y > 0.f ? acc.y : expm1f(acc.y)) + r.y;
    o.z = (acc.z > 0.f ? acc.z : expm1f(acc.z)) + r.z;
    o.w = (acc.w > 0.f ? acc.w : expm1f(acc.w)) + r.w;
    *(float4*)op = o;
}

extern "C" void kernel_launch(void* const* d_in, const int* in_sizes, int n_in,
                              void* d_out, int out_size, void* d_ws, size_t ws_size,
                              hipStream_t stream) {
    const float* x    = (const float*)d_in[0];
    const int*   ei   = (const int*)d_in[1];
    const float* ew   = (const float*)d_in[2];
    const float* lw   = (const float*)d_in[3];
    const float* attl = (const float*)d_in[4];
    const float* attr = (const float*)d_in[5];
    const float* lrw  = (const float*)d_in[6];
    float* out = (float*)d_out;
    const int* src = ei;
    const int* dst = ei + NE;

    char* w = (char*)d_ws;
    auto alloc = [&](size_t bytes) { char* p = w; w += (bytes + 255) & ~(size_t)255; return p; };
    unsigned short* WTh = (unsigned short*)alloc((size_t)NCOL * 128 * 2);
    unsigned short* WTl = (unsigned short*)alloc((size_t)NCOL * 128 * 2);
    unsigned short* hbf = (unsigned short*)alloc((size_t)NN * TOT * 2);
    float* al     = (float*)alloc((size_t)NN * 4 * 4);
    float* ar     = (float*)alloc((size_t)NN * 4 * 4);
    int*   deg    = (int*)alloc((size_t)NN * 4);
    int*   rowptr = (int*)alloc((size_t)(NN + 1) * 4);
    int*   cursor = (int*)alloc((size_t)NN * 4);
    int*   bsum   = (int*)alloc((size_t)512 * 4);
    int*   psrc   = (int*)alloc((size_t)NE * 4);
    float* palpha = (float*)alloc((size_t)NE * 4 * 4);
    size_t needed = (size_t)(w - (char*)d_ws);
    if (ws_size < needed) return;  // fail loudly (validation will catch)

    hipMemsetAsync(deg, 0, (size_t)NN * 4, stream);

    k0_wt<<<(NCOL * 128 + 255) / 256, 256, 0, stream>>>(lw, lrw, attl, attr, WTh, WTl);
    k1_mfma<<<(NN + 127) / 128, 256, 0, stream>>>(x, WTh, WTl, hbf, out, al, ar);
    khist<<<(NE + 255) / 256, 256, 0, stream>>>(dst, deg);
    kscan_block<<<NB, 256, 0, stream>>>(deg, bsum);
    kscan_top<<<1, 512, 0, stream>>>(bsum);
    kscan_final<<<NB, 256, 0, stream>>>(deg, bsum, rowptr, cursor);
    kfill<<<(NE + 255) / 256, 256, 0, stream>>>(src, dst, ew, al, ar, cursor, psrc, palpha);
    kagg<<<(NN + 15) / 16, 256, 0, stream>>>(rowptr, psrc, palpha, hbf, out);
}